// Round 1
// baseline (292.915 us; speedup 1.0000x reference)
//
#include <hip/hip_runtime.h>

// Attention: B=8, N=4096, D=64, fp32 in/out, causal + padding mask.
// Flash-attention, bf16 MFMA (16x16x32), S^T orientation, online softmax.

#define BATCH 8
#define SEQ   4096
#define DIM   64

typedef __attribute__((ext_vector_type(8))) short bf16x8;
typedef __attribute__((ext_vector_type(4))) float f32x4;

__device__ inline short f2bf(float f) {
    unsigned u = __builtin_bit_cast(unsigned, f);
    u += 0x7FFFu + ((u >> 16) & 1u);   // RNE
    return (short)(u >> 16);
}

__device__ inline float fast_exp2(float x) {
#if __has_builtin(__builtin_amdgcn_exp2f)
    return __builtin_amdgcn_exp2f(x);
#else
    return exp2f(x);
#endif
}

// LDS cell stride 65 (not 64): byte stride 65*16=1040 -> bank stride 4 per
// chunk, so fragment ds_read_b128 across 16 lanes is conflict-free.
__global__ __launch_bounds__(256, 2)
void attn_fwd(const float* __restrict__ qg, const float* __restrict__ kg,
              const float* __restrict__ vg, const int* __restrict__ mg,
              float* __restrict__ og) {
    __shared__ short Klds[519 * 8];   // [dchunk 0..7][key 0..63][jd 0..7], cell=c*65+key
    __shared__ short Vlds[519 * 8];   // [kchunk 0..7][d 0..63][jk 0..7],  cell=kc*65+d
    __shared__ short Plds[4 * 16 * 72]; // per-wave [q 0..15][key 0..63 +8 pad]
    __shared__ float Mlds[64];        // padding-mask addend (0 or -1e30)

    const int t    = threadIdx.x;
    const int w    = t >> 6;      // wave 0..3
    const int L    = t & 63;      // lane
    const int c15  = L & 15;
    const int quad = L >> 4;
    const int b    = blockIdx.y;
    const int qb   = (int)gridDim.x - 1 - (int)blockIdx.x; // big blocks first
    const int qbase = qb * 64;

    const float* qp = qg + (size_t)b * SEQ * DIM;
    const float* kp = kg + (size_t)b * SEQ * DIM;
    const float* vp = vg + (size_t)b * SEQ * DIM;
    const int*   mp = mg + (size_t)b * SEQ;

    const int qrow = qbase + w * 16 + c15;   // this lane's q column (S^T orientation)
    const float qscale = 0.125f * 1.44269504088896340736f; // 1/sqrt(64) * log2(e)

    // Q fragments, scale folded in. B-frag layout: n=lane&15 (=q), k=quad*8+j (+32c)
    bf16x8 Qf[2];
#pragma unroll
    for (int c = 0; c < 2; ++c) {
        const float* src = qp + (size_t)qrow * DIM + c * 32 + quad * 8;
        float4 x = *(const float4*)(src);
        float4 y = *(const float4*)(src + 4);
        bf16x8 f;
        f[0] = f2bf(x.x * qscale); f[1] = f2bf(x.y * qscale);
        f[2] = f2bf(x.z * qscale); f[3] = f2bf(x.w * qscale);
        f[4] = f2bf(y.x * qscale); f[5] = f2bf(y.y * qscale);
        f[6] = f2bf(y.z * qscale); f[7] = f2bf(y.w * qscale);
        Qf[c] = f;
    }

    float mrun = -1e30f, lrun = 0.0f;
    f32x4 Oacc[4];
#pragma unroll
    for (int nb = 0; nb < 4; ++nb) Oacc[nb] = (f32x4){0.f, 0.f, 0.f, 0.f};

    for (int kt = 0; kt <= qb; ++kt) {
        __syncthreads();   // previous iteration's LDS reads done
        // ---- stage K,V tile (64 keys x 64 d) fp32->bf16, coalesced global reads
#pragma unroll
        for (int i = 0; i < 4; ++i) {
            int flat = i * 256 + t;          // 0..1023
            int key  = flat >> 4;            // 0..63
            int d0   = (flat & 15) * 4;      // 0..60
            const float4 kv = *(const float4*)(kp + (size_t)(kt * 64 + key) * DIM + d0);
            short4 ks;
            ks.x = f2bf(kv.x); ks.y = f2bf(kv.y); ks.z = f2bf(kv.z); ks.w = f2bf(kv.w);
            *(short4*)&Klds[((d0 >> 3) * 65 + key) * 8 + (d0 & 7)] = ks;
            const float4 vv = *(const float4*)(vp + (size_t)(kt * 64 + key) * DIM + d0);
            int kc = key >> 3, jk = key & 7; // transposed scatter (known 2B-write conflicts)
            Vlds[(kc * 65 + d0 + 0) * 8 + jk] = f2bf(vv.x);
            Vlds[(kc * 65 + d0 + 1) * 8 + jk] = f2bf(vv.y);
            Vlds[(kc * 65 + d0 + 2) * 8 + jk] = f2bf(vv.z);
            Vlds[(kc * 65 + d0 + 3) * 8 + jk] = f2bf(vv.w);
        }
        if (t < 64) Mlds[t] = mp[kt * 64 + t] ? 0.0f : -1e30f;
        __syncthreads();

        // ---- S^T = K @ Q^T : rows = keys (kb*16 + quad*4 + r), col = q (=c15)
        f32x4 sacc[4];
#pragma unroll
        for (int kb = 0; kb < 4; ++kb) sacc[kb] = (f32x4){0.f, 0.f, 0.f, 0.f};
#pragma unroll
        for (int c = 0; c < 2; ++c) {
#pragma unroll
            for (int kb = 0; kb < 4; ++kb) {
                bf16x8 kf = *(const bf16x8*)&Klds[((quad + 4 * c) * 65 + kb * 16 + c15) * 8];
                sacc[kb] = __builtin_amdgcn_mfma_f32_16x16x32_bf16(kf, Qf[c], sacc[kb], 0, 0, 0);
            }
        }

        // ---- masks + online softmax (per-lane column q = qrow)
        float sv[4][4];
        float tmax = -1e30f;
        const bool diag = (kt == qb);
#pragma unroll
        for (int kb = 0; kb < 4; ++kb) {
            float4 ma = *(const float4*)&Mlds[kb * 16 + quad * 4];
            float mar[4] = {ma.x, ma.y, ma.z, ma.w};
#pragma unroll
            for (int r = 0; r < 4; ++r) {
                float s = sacc[kb][r] + mar[r];
                if (diag) {
                    int keyg = kt * 64 + kb * 16 + quad * 4 + r;
                    if (keyg > qrow) s = -1e30f;
                }
                sv[kb][r] = s;
                tmax = fmaxf(tmax, s);
            }
        }
        tmax = fmaxf(tmax, __shfl_xor(tmax, 16));
        tmax = fmaxf(tmax, __shfl_xor(tmax, 32));
        float mnew  = fmaxf(mrun, tmax);
        float alpha = fast_exp2(mrun - mnew);
        mrun = mnew;

        float tsum = 0.f;
#pragma unroll
        for (int kb = 0; kb < 4; ++kb) {
            float p0 = fast_exp2(sv[kb][0] - mnew);
            float p1 = fast_exp2(sv[kb][1] - mnew);
            float p2 = fast_exp2(sv[kb][2] - mnew);
            float p3 = fast_exp2(sv[kb][3] - mnew);
            tsum += (p0 + p1) + (p2 + p3);
            short4 pb;
            pb.x = f2bf(p0); pb.y = f2bf(p1); pb.z = f2bf(p2); pb.w = f2bf(p3);
            // write P[q=c15][key=kb*16+quad*4 .. +3]
            *(short4*)&Plds[((w * 16 + c15) * 72) + kb * 16 + quad * 4] = pb;
        }
        tsum += __shfl_xor(tsum, 16);
        tsum += __shfl_xor(tsum, 32);
        lrun = lrun * alpha + tsum;

        // alpha for this lane's O rows (q = quad*4 + r): fetch from lane with c15==quad*4+r
        float ar[4];
#pragma unroll
        for (int r = 0; r < 4; ++r)
            ar[r] = __shfl(alpha, (L & 48) + ((L & 48) >> 2) + r);
#pragma unroll
        for (int nb = 0; nb < 4; ++nb) {
#pragma unroll
            for (int r = 0; r < 4; ++r) Oacc[nb][r] *= ar[r];
        }

        // ---- O += P @ V   (A = P from LDS round-trip, B = V chunk-swizzled)
#pragma unroll
        for (int c = 0; c < 2; ++c) {
            bf16x8 pf = *(const bf16x8*)&Plds[((w * 16 + c15) * 72) + c * 32 + quad * 8];
#pragma unroll
            for (int nb = 0; nb < 4; ++nb) {
                bf16x8 vf = *(const bf16x8*)&Vlds[((quad + 4 * c) * 65 + nb * 16 + c15) * 8];
                Oacc[nb] = __builtin_amdgcn_mfma_f32_16x16x32_bf16(pf, vf, Oacc[nb], 0, 0, 0);
            }
        }
    }

    // ---- epilogue: O / l, write fp32
    float inv[4];
#pragma unroll
    for (int r = 0; r < 4; ++r) {
        float lr = __shfl(lrun, (L & 48) + ((L & 48) >> 2) + r);
        inv[r] = 1.0f / lr;
    }
    float* op = og + (size_t)b * SEQ * DIM;
#pragma unroll
    for (int r = 0; r < 4; ++r) {
        int row = qbase + w * 16 + quad * 4 + r;
#pragma unroll
        for (int nb = 0; nb < 4; ++nb)
            op[(size_t)row * DIM + nb * 16 + c15] = Oacc[nb][r] * inv[r];
    }
}

extern "C" void kernel_launch(void* const* d_in, const int* in_sizes, int n_in,
                              void* d_out, int out_size, void* d_ws, size_t ws_size,
                              hipStream_t stream) {
    (void)in_sizes; (void)n_in; (void)d_ws; (void)ws_size; (void)out_size;
    const float* q = (const float*)d_in[0];
    const float* k = (const float*)d_in[1];
    const float* v = (const float*)d_in[2];
    const int*   m = (const int*)d_in[3];
    float* o = (float*)d_out;
    dim3 grid(SEQ / 64, BATCH);
    attn_fwd<<<grid, 256, 0, stream>>>(q, k, v, m, o);
}

// Round 2
// 212.722 us; speedup vs baseline: 1.3770x; 1.3770x over previous
//
#include <hip/hip_runtime.h>

// Attention: B=8, N=4096, D=64, fp32 in/out, causal + padding mask.
// Flash-attention, bf16 MFMA (16x16x32), S^T orientation, online softmax.
// R2: double-buffered LDS with register prefetch (1 barrier/iter, global
//     latency overlapped) + V staged as cell(d,kc)=d*9+kc to cut the
//     8-way transpose-write bank conflicts to 4-way.

#define BATCH 8
#define SEQ   4096
#define DIM   64

typedef __attribute__((ext_vector_type(8))) short bf16x8;
typedef __attribute__((ext_vector_type(4))) float f32x4;

__device__ inline short f2bf(float f) {
    unsigned u = __builtin_bit_cast(unsigned, f);
    u += 0x7FFFu + ((u >> 16) & 1u);   // RNE
    return (short)(u >> 16);
}

__device__ inline float fast_exp2(float x) {
#if __has_builtin(__builtin_amdgcn_exp2f)
    return __builtin_amdgcn_exp2f(x);
#else
    return exp2f(x);
#endif
}

__global__ __launch_bounds__(256, 2)
void attn_fwd(const float* __restrict__ qg, const float* __restrict__ kg,
              const float* __restrict__ vg, const int* __restrict__ mg,
              float* __restrict__ og) {
    // K: cell(dchunk 0..7, key 0..63) = dchunk*65 + key, 8 shorts/cell
    __shared__ short Klds[2][519 * 8];
    // V: cell(d 0..63, kchunk 0..7) = d*9 + kchunk, 8 shorts/cell (keys j in cell)
    __shared__ short Vlds[2][576 * 8];
    __shared__ short Plds[4 * 16 * 72]; // per-wave [q 0..15][key 0..63 +8 pad]
    __shared__ float Mlds[2][64];       // padding-mask addend (0 or -1e30)

    const int t    = threadIdx.x;
    const int w    = t >> 6;      // wave 0..3
    const int L    = t & 63;      // lane
    const int c15  = L & 15;
    const int quad = L >> 4;
    const int b    = blockIdx.y;
    const int qb   = (int)gridDim.x - 1 - (int)blockIdx.x; // big blocks first
    const int qbase = qb * 64;

    const float* qp = qg + (size_t)b * SEQ * DIM;
    const float* kp = kg + (size_t)b * SEQ * DIM;
    const float* vp = vg + (size_t)b * SEQ * DIM;
    const int*   mp = mg + (size_t)b * SEQ;

    const int qrow = qbase + w * 16 + c15;   // this lane's q column (S^T orientation)
    const float qscale = 0.125f * 1.44269504088896340736f; // 1/sqrt(64) * log2(e)

    // Q fragments, scale folded in. B-frag layout: n=lane&15 (=q), k=quad*8+j (+32c)
    bf16x8 Qf[2];
#pragma unroll
    for (int c = 0; c < 2; ++c) {
        const float* src = qp + (size_t)qrow * DIM + c * 32 + quad * 8;
        float4 x = *(const float4*)(src);
        float4 y = *(const float4*)(src + 4);
        bf16x8 f;
        f[0] = f2bf(x.x * qscale); f[1] = f2bf(x.y * qscale);
        f[2] = f2bf(x.z * qscale); f[3] = f2bf(x.w * qscale);
        f[4] = f2bf(y.x * qscale); f[5] = f2bf(y.y * qscale);
        f[6] = f2bf(y.z * qscale); f[7] = f2bf(y.w * qscale);
        Qf[c] = f;
    }

    // per-thread staging coordinates (same for every tile)
    int skey[4], sd0[4];
#pragma unroll
    for (int i = 0; i < 4; ++i) {
        int flat = i * 256 + t;
        skey[i] = flat >> 4;         // 0..63
        sd0[i]  = (flat & 15) * 4;   // 0..60
    }

    // convert prefetched registers and write to LDS buffer `bs`
    auto writebuf = [&](int bs, const float4* kr, const float4* vr, int mreg) {
#pragma unroll
        for (int i = 0; i < 4; ++i) {
            const int key = skey[i], d0 = sd0[i];
            short4 ks;
            ks.x = f2bf(kr[i].x); ks.y = f2bf(kr[i].y);
            ks.z = f2bf(kr[i].z); ks.w = f2bf(kr[i].w);
            *(short4*)&Klds[bs][((d0 >> 3) * 65 + key) * 8 + (d0 & 7)] = ks;
            const int kc = key >> 3, jk = key & 7;
            Vlds[bs][((d0 + 0) * 9 + kc) * 8 + jk] = f2bf(vr[i].x);
            Vlds[bs][((d0 + 1) * 9 + kc) * 8 + jk] = f2bf(vr[i].y);
            Vlds[bs][((d0 + 2) * 9 + kc) * 8 + jk] = f2bf(vr[i].z);
            Vlds[bs][((d0 + 3) * 9 + kc) * 8 + jk] = f2bf(vr[i].w);
        }
        if (t < 64) Mlds[bs][t] = mreg ? 0.0f : -1e30f;
    };

    float mrun = -1e30f, lrun = 0.0f;
    f32x4 Oacc[4];
#pragma unroll
    for (int nb = 0; nb < 4; ++nb) Oacc[nb] = (f32x4){0.f, 0.f, 0.f, 0.f};

    // ---- prologue: fetch + stage tile 0
    float4 kreg[4], vreg[4];
    int mreg = 1;
#pragma unroll
    for (int i = 0; i < 4; ++i) {
        kreg[i] = *(const float4*)(kp + (size_t)skey[i] * DIM + sd0[i]);
        vreg[i] = *(const float4*)(vp + (size_t)skey[i] * DIM + sd0[i]);
    }
    if (t < 64) mreg = mp[t];
    writebuf(0, kreg, vreg, mreg);

    for (int kt = 0; kt <= qb; ++kt) {
        __syncthreads();   // buffer kt&1 fully staged; buffer (kt+1)&1 free
        const int cur = kt & 1;
        const bool pre = kt < qb;

        // ---- issue prefetch for tile kt+1 (latency overlapped with compute)
        if (pre) {
            const float* kpt = kp + (size_t)(kt + 1) * 64 * DIM;
            const float* vpt = vp + (size_t)(kt + 1) * 64 * DIM;
#pragma unroll
            for (int i = 0; i < 4; ++i) {
                kreg[i] = *(const float4*)(kpt + (size_t)skey[i] * DIM + sd0[i]);
                vreg[i] = *(const float4*)(vpt + (size_t)skey[i] * DIM + sd0[i]);
            }
            if (t < 64) mreg = mp[(kt + 1) * 64 + t];
        }

        // ---- S^T = K @ Q^T : rows = keys (kb*16 + quad*4 + r), col = q (=c15)
        f32x4 sacc[4];
#pragma unroll
        for (int kb = 0; kb < 4; ++kb) sacc[kb] = (f32x4){0.f, 0.f, 0.f, 0.f};
#pragma unroll
        for (int c = 0; c < 2; ++c) {
#pragma unroll
            for (int kb = 0; kb < 4; ++kb) {
                bf16x8 kf = *(const bf16x8*)&Klds[cur][((quad + 4 * c) * 65 + kb * 16 + c15) * 8];
                sacc[kb] = __builtin_amdgcn_mfma_f32_16x16x32_bf16(kf, Qf[c], sacc[kb], 0, 0, 0);
            }
        }

        // ---- masks + online softmax (per-lane column q = qrow)
        float sv[4][4];
        float tmax = -1e30f;
        const bool diag = (kt == qb);
#pragma unroll
        for (int kb = 0; kb < 4; ++kb) {
            float4 ma = *(const float4*)&Mlds[cur][kb * 16 + quad * 4];
            float mar[4] = {ma.x, ma.y, ma.z, ma.w};
#pragma unroll
            for (int r = 0; r < 4; ++r) {
                float s = sacc[kb][r] + mar[r];
                if (diag) {
                    int keyg = kt * 64 + kb * 16 + quad * 4 + r;
                    if (keyg > qrow) s = -1e30f;
                }
                sv[kb][r] = s;
                tmax = fmaxf(tmax, s);
            }
        }
        tmax = fmaxf(tmax, __shfl_xor(tmax, 16));
        tmax = fmaxf(tmax, __shfl_xor(tmax, 32));
        float mnew  = fmaxf(mrun, tmax);
        float alpha = fast_exp2(mrun - mnew);
        mrun = mnew;

        float tsum = 0.f;
#pragma unroll
        for (int kb = 0; kb < 4; ++kb) {
            float p0 = fast_exp2(sv[kb][0] - mnew);
            float p1 = fast_exp2(sv[kb][1] - mnew);
            float p2 = fast_exp2(sv[kb][2] - mnew);
            float p3 = fast_exp2(sv[kb][3] - mnew);
            tsum += (p0 + p1) + (p2 + p3);
            short4 pb;
            pb.x = f2bf(p0); pb.y = f2bf(p1); pb.z = f2bf(p2); pb.w = f2bf(p3);
            // write P[q=c15][key=kb*16+quad*4 .. +3]  (per-wave region, no barrier)
            *(short4*)&Plds[((w * 16 + c15) * 72) + kb * 16 + quad * 4] = pb;
        }
        tsum += __shfl_xor(tsum, 16);
        tsum += __shfl_xor(tsum, 32);
        lrun = lrun * alpha + tsum;

        // alpha for this lane's O rows (q = quad*4 + r): from lane with c15==quad*4+r
        float ar[4];
#pragma unroll
        for (int r = 0; r < 4; ++r)
            ar[r] = __shfl(alpha, (L & 48) + ((L & 48) >> 2) + r);
#pragma unroll
        for (int nb = 0; nb < 4; ++nb) {
#pragma unroll
            for (int r = 0; r < 4; ++r) Oacc[nb][r] *= ar[r];
        }

        // ---- O += P @ V   (A = P from LDS round-trip, B = V cell(d,kc)=d*9+kc)
#pragma unroll
        for (int c = 0; c < 2; ++c) {
            bf16x8 pf = *(const bf16x8*)&Plds[((w * 16 + c15) * 72) + c * 32 + quad * 8];
#pragma unroll
            for (int nb = 0; nb < 4; ++nb) {
                bf16x8 vf = *(const bf16x8*)&Vlds[cur][((nb * 16 + c15) * 9 + quad + 4 * c) * 8];
                Oacc[nb] = __builtin_amdgcn_mfma_f32_16x16x32_bf16(pf, vf, Oacc[nb], 0, 0, 0);
            }
        }

        // ---- drain prefetch into the other buffer
        if (pre) writebuf((kt + 1) & 1, kreg, vreg, mreg);
    }

    // ---- epilogue: O / l, write fp32
    float inv[4];
#pragma unroll
    for (int r = 0; r < 4; ++r) {
        float lr = __shfl(lrun, (L & 48) + ((L & 48) >> 2) + r);
        inv[r] = 1.0f / lr;
    }
    float* op = og + (size_t)b * SEQ * DIM;
#pragma unroll
    for (int r = 0; r < 4; ++r) {
        int row = qbase + w * 16 + quad * 4 + r;
#pragma unroll
        for (int nb = 0; nb < 4; ++nb)
            op[(size_t)row * DIM + nb * 16 + c15] = Oacc[nb][r] * inv[r];
    }
}

extern "C" void kernel_launch(void* const* d_in, const int* in_sizes, int n_in,
                              void* d_out, int out_size, void* d_ws, size_t ws_size,
                              hipStream_t stream) {
    (void)in_sizes; (void)n_in; (void)d_ws; (void)ws_size; (void)out_size;
    const float* q = (const float*)d_in[0];
    const float* k = (const float*)d_in[1];
    const float* v = (const float*)d_in[2];
    const int*   m = (const int*)d_in[3];
    float* o = (float*)d_out;
    dim3 grid(SEQ / 64, BATCH);
    attn_fwd<<<grid, 256, 0, stream>>>(q, k, v, m, o);
}